// Round 9
// baseline (149.177 us; speedup 1.0000x reference)
//
#include <hip/hip_runtime.h>

// QKBmm: out[b,m,q,kv] = sum_h q[b,m,q,h] * k[b,m,kv,h]
// B=2, M=16, QT=1024, KVT=4096, H=128. fp32 in/out, bf16 MFMA compute.
// Write-bound: 512 MB out, inputs L3-resident. Floor ~88us @6.7TB/s.
// R6 WIN 122.6us (4 blk/CU). R7 FAILED (spill). R8 NEUTRAL (5 blk/CU) —
//   occupancy saturated. Measured round = write(6.2us) + stage(3.5us)
//   SERIALIZED: stores drain at kernel end (vmcnt(0) before endpgm) blocks
//   the slot; next block stages only after.
// R9: persistent-ish blocks, 16 tiles each, counted-vmcnt pipeline:
//   stores stay in flight across steps (never vmcnt(0) in loop); A staged
//   once per block; stores split 8+8 so every step has uniform vmcnt(8).

#define QT   1024
#define KVT  4096
#define HD   128

using bf16x8 = __attribute__((ext_vector_type(8))) __bf16;
using bf16x4 = __attribute__((ext_vector_type(4))) __bf16;
using f32x4  = __attribute__((ext_vector_type(4))) float;

#define STAGE_ISSUE(bv, n0src, h)                                              \
    {                                                                          \
        const float4* Kt4 =                                                    \
            reinterpret_cast<const float4*>(Kb + (size_t)(n0src) * HD);        \
        _Pragma("unroll")                                                      \
        for (int it = 0; it < 8; ++it) {                                       \
            int f = it * 256 + t, row = f >> 4, c4 = f & 15;                   \
            bv[it] = Kt4[row * 32 + (h) * 16 + c4];                            \
        }                                                                      \
    }

#define STAGE_WRITE(bv)                                                        \
    {                                                                          \
        _Pragma("unroll")                                                      \
        for (int it = 0; it < 8; ++it) {                                       \
            int f = it * 256 + t, row = f >> 4, c4 = f & 15;                   \
            int e = (row * 64 + c4 * 4) ^ ((row & 7) << 3);                    \
            *reinterpret_cast<bf16x4*>(&Bs[e]) =                               \
                bf16x4{(__bf16)bv[it].x, (__bf16)bv[it].y,                     \
                       (__bf16)bv[it].z, (__bf16)bv[it].w};                    \
        }                                                                      \
    }

#define COMPUTE(h)                                                             \
    {                                                                          \
        _Pragma("unroll")                                                      \
        for (int ks = 0; ks < 2; ++ks) {                                       \
            const int kcol = ks * 32 + lg * 8;                                 \
            bf16x8 bfr[2];                                                     \
            _Pragma("unroll")                                                  \
            for (int ni = 0; ni < 2; ++ni) {                                   \
                int r = wn + ni * 16 + lr;                                     \
                int e = (r * 64 + kcol) ^ ((r & 7) << 3);                      \
                bfr[ni] = *reinterpret_cast<const bf16x8*>(&Bs[e]);            \
            }                                                                  \
            _Pragma("unroll")                                                  \
            for (int mi = 0; mi < 2; ++mi) {                                   \
                int r = mi * 16 + lr;                                          \
                int e = (r * 128 + (h) * 64 + kcol) ^ ((r & 7) << 3);          \
                bf16x8 af = *reinterpret_cast<const bf16x8*>(&As[e]);          \
                _Pragma("unroll")                                              \
                for (int ni = 0; ni < 2; ++ni)                                 \
                    acc[mi][ni] = __builtin_amdgcn_mfma_f32_16x16x32_bf16(     \
                        af, bfr[ni], acc[mi][ni], 0, 0, 0);                    \
            }                                                                  \
        }                                                                      \
    }

// mi=0 rows: m0 + lg*4 + j ; proven scalar-NT-dword pattern
#define STORE_MI0(n0cur)                                                       \
    {                                                                          \
        _Pragma("unroll")                                                      \
        for (int j = 0; j < 4; ++j) {                                          \
            int row = m0 + lg * 4 + j;                                         \
            float* rp = Cp + (size_t)row * KVT + (n0cur) + wn;                 \
            _Pragma("unroll")                                                  \
            for (int ni = 0; ni < 2; ++ni)                                     \
                __builtin_nontemporal_store(acc[0][ni][j], rp + ni * 16 + lr); \
        }                                                                      \
    }

// mi=1 rows of the PREVIOUS tile, from pend
#define STORE_PEND(n0p)                                                        \
    {                                                                          \
        _Pragma("unroll")                                                      \
        for (int j = 0; j < 4; ++j) {                                          \
            int row = m0 + 16 + lg * 4 + j;                                    \
            float* rp = Cp + (size_t)row * KVT + (n0p) + wn;                   \
            _Pragma("unroll")                                                  \
            for (int ni = 0; ni < 2; ++ni)                                     \
                __builtin_nontemporal_store(pend[ni][j], rp + ni * 16 + lr);   \
        }                                                                      \
    }

#define WAIT_VM8()  asm volatile("s_waitcnt vmcnt(8)" ::: "memory")
#define WAIT_VM0()  asm volatile("s_waitcnt vmcnt(0)" ::: "memory")
#define WAIT_LGKM() asm volatile("s_waitcnt lgkmcnt(0)" ::: "memory")
#define BAR()       __builtin_amdgcn_s_barrier()

__global__ __launch_bounds__(256, 4)
void QKBmm_74062416052397_kernel(const float* __restrict__ q,
                                 const float* __restrict__ k,
                                 float* __restrict__ out) {
    __shared__ __bf16 As[32 * 128];   // 8 KB, staged once per block (q tile)
    __shared__ __bf16 Bs[128 * 64];   // 16 KB, restaged every half-step (k)

    const int t = threadIdx.x;         // 0..255
    const int b = blockIdx.x;          // 0..2047

    // XCD-chunked mapping; each block owns 16 consecutive n-tiles of one
    // (bm, m-row) stripe: full A reuse, k slices L2/L3-served.
    const int xcd = b & 7, w = b >> 3;             // w: 0..255
    const int mtt = (w >> 1) & 31;                 // 32-row q tile
    const int bm  = xcd * 4 + (w >> 6);            // batch*M
    const int m0  = mtt * 32;
    const int ntb = (w & 1) * 16;                  // first of 16 n-tiles

    const int lane = t & 63, wid = t >> 6;
    const int wn = wid * 32;           // wave col offset (4 waves x 32)
    const int lr = lane & 15, lg = lane >> 4;

    const float4* __restrict__ Q4 = reinterpret_cast<const float4*>(
        q + ((size_t)bm * QT + m0) * HD);
    const float* __restrict__ Kb = k + (size_t)bm * KVT * HD;
    float* __restrict__ Cp = out + (size_t)bm * QT * KVT;

    float4 bvA[8], bvB[8];
    f32x4 acc[2][2] = {};
    f32x4 pend[2];

    // ---- Prologue: A loads, B(t0,h0) loads, A cvt+ds_write ----
    {
        float4 av[4];
#pragma unroll
        for (int it = 0; it < 4; ++it) av[it] = Q4[it * 256 + t];
        STAGE_ISSUE(bvA, ntb * 128, 0);
#pragma unroll
        for (int it = 0; it < 4; ++it) {
            int f = it * 256 + t, row = f >> 5, c4 = f & 31;
            int e = (row * 128 + c4 * 4) ^ ((row & 7) << 3);
            *reinterpret_cast<bf16x4*>(&As[e]) =
                bf16x4{(__bf16)av[it].x, (__bf16)av[it].y,
                       (__bf16)av[it].z, (__bf16)av[it].w};
        }
        WAIT_LGKM();
        BAR();
    }

    // ---- Peeled tile 0 (non-uniform store counts live only here) ----
    {
        // h0
        WAIT_VM0();                    // bvA ready
        STAGE_WRITE(bvA);
        STAGE_ISSUE(bvB, ntb * 128, 1);
        WAIT_LGKM(); BAR();
        COMPUTE(0);
        BAR();
        // h1
        WAIT_VM0();                    // bvB ready
        STAGE_WRITE(bvB);
        STAGE_ISSUE(bvA, (ntb + 1) * 128, 0);
        WAIT_LGKM(); BAR();
        COMPUTE(1);
        STORE_MI0(ntb * 128);          // 8 NT stores, stay in flight
        pend[0] = acc[1][0]; pend[1] = acc[1][1];
#pragma unroll
        for (int mi = 0; mi < 2; ++mi)
#pragma unroll
            for (int ni = 0; ni < 2; ++ni) acc[mi][ni] = f32x4{0.f, 0.f, 0.f, 0.f};
        BAR();
    }

    int n0_prev = ntb * 128;
    for (int tt = 1; tt < 16; ++tt) {
        const int n0c = (ntb + tt) * 128;
        // ---- h0 ----
        WAIT_VM8();                    // bvA done; 8 stores may remain
        STAGE_WRITE(bvA);
        STAGE_ISSUE(bvB, n0c, 1);
        WAIT_LGKM(); BAR();
        COMPUTE(0);
        STORE_PEND(n0_prev);           // 8 NT stores (prev tile mi=1)
        BAR();
        // ---- h1 ----
        WAIT_VM8();                    // bvB done; 8 stores may remain
        STAGE_WRITE(bvB);
        if (tt < 15) STAGE_ISSUE(bvA, (n0c + 128), 0);
        WAIT_LGKM(); BAR();
        COMPUTE(1);
        STORE_MI0(n0c);                // 8 NT stores
        pend[0] = acc[1][0]; pend[1] = acc[1][1];
#pragma unroll
        for (int mi = 0; mi < 2; ++mi)
#pragma unroll
            for (int ni = 0; ni < 2; ++ni) acc[mi][ni] = f32x4{0.f, 0.f, 0.f, 0.f};
        n0_prev = n0c;
        BAR();
    }
    STORE_PEND(n0_prev);               // last tile's mi=1 half
}

extern "C" void kernel_launch(void* const* d_in, const int* in_sizes, int n_in,
                              void* d_out, int out_size, void* d_ws, size_t ws_size,
                              hipStream_t stream) {
    const float* q = (const float*)d_in[0];
    const float* k = (const float*)d_in[1];
    float* out = (float*)d_out;

    QKBmm_74062416052397_kernel<<<dim3(2048), dim3(256), 0, stream>>>(q, k, out);
}